// Round 1
// baseline (4717.146 us; speedup 1.0000x reference)
//
#include <hip/hip_runtime.h>
#include <hip/hip_bf16.h>

#define N_NODES 10000
#define N_EDGES 40000
#define NLAYERS 5

typedef __bf16 bf16x8 __attribute__((ext_vector_type(8)));
typedef float  f32x4  __attribute__((ext_vector_type(4)));

__device__ inline bf16x8 cvt8(float4 a, float4 b) {
    bf16x8 r;
    r[0] = (__bf16)a.x; r[1] = (__bf16)a.y; r[2] = (__bf16)a.z; r[3] = (__bf16)a.w;
    r[4] = (__bf16)b.x; r[5] = (__bf16)b.y; r[6] = (__bf16)b.z; r[7] = (__bf16)b.w;
    return r;
}

// C[M x Nc] = A[M x K] (f32) @ W[Nc x K]^T (f32), bf16 MFMA, fp32 accum.
// grid: (ceil(M/64), Nc/64), block 256. OUTBF: store bf16 into Ch else f32 into Cf.
template<bool OUTBF>
__global__ __launch_bounds__(256) void gemm_bt(
    const float* __restrict__ A, const float* __restrict__ W,
    float* __restrict__ Cf, __bf16* __restrict__ Ch,
    int M, int K, int ldc, int coloff)
{
    const int lane = threadIdx.x & 63;
    const int wv   = threadIdx.x >> 6;
    const int r    = lane & 15;
    const int kg   = (lane >> 4) * 8;          // 0,8,16,24
    const int row  = blockIdx.x * 64 + wv * 16 + r;
    const int colb = blockIdx.y * 64;
    const bool aok = row < M;

    const float* ap = A + (size_t)row * K + kg;
    const float* w0 = W + (size_t)(colb + r) * K + kg;
    const float* w1 = w0 + (size_t)16 * K;
    const float* w2 = w0 + (size_t)32 * K;
    const float* w3 = w0 + (size_t)48 * K;

    f32x4 acc0 = {0.f,0.f,0.f,0.f}, acc1 = {0.f,0.f,0.f,0.f};
    f32x4 acc2 = {0.f,0.f,0.f,0.f}, acc3 = {0.f,0.f,0.f,0.f};
    const float4 z4 = {0.f,0.f,0.f,0.f};

    for (int kk = 0; kk < K; kk += 32) {
        float4 a0 = aok ? *(const float4*)(ap + kk)     : z4;
        float4 a1 = aok ? *(const float4*)(ap + kk + 4) : z4;
        bf16x8 af  = cvt8(a0, a1);
        bf16x8 bf0 = cvt8(*(const float4*)(w0 + kk), *(const float4*)(w0 + kk + 4));
        bf16x8 bf1 = cvt8(*(const float4*)(w1 + kk), *(const float4*)(w1 + kk + 4));
        bf16x8 bf2 = cvt8(*(const float4*)(w2 + kk), *(const float4*)(w2 + kk + 4));
        bf16x8 bf3 = cvt8(*(const float4*)(w3 + kk), *(const float4*)(w3 + kk + 4));
        acc0 = __builtin_amdgcn_mfma_f32_16x16x32_bf16(af, bf0, acc0, 0, 0, 0);
        acc1 = __builtin_amdgcn_mfma_f32_16x16x32_bf16(af, bf1, acc1, 0, 0, 0);
        acc2 = __builtin_amdgcn_mfma_f32_16x16x32_bf16(af, bf2, acc2, 0, 0, 0);
        acc3 = __builtin_amdgcn_mfma_f32_16x16x32_bf16(af, bf3, acc3, 0, 0, 0);
    }

    const int orow0 = blockIdx.x * 64 + wv * 16 + (lane >> 4) * 4;
    #pragma unroll
    for (int rr = 0; rr < 4; ++rr) {
        int orow = orow0 + rr;
        if (orow < M) {
            size_t base = (size_t)orow * ldc + coloff + colb + r;
            if (OUTBF) {
                Ch[base]      = (__bf16)acc0[rr];
                Ch[base + 16] = (__bf16)acc1[rr];
                Ch[base + 32] = (__bf16)acc2[rr];
                Ch[base + 48] = (__bf16)acc3[rr];
            } else {
                Cf[base]      = acc0[rr];
                Cf[base + 16] = acc1[rr];
                Cf[base + 32] = acc2[rr];
                Cf[base + 48] = acc3[rr];
            }
        }
    }
}

// Per (edge e, row a): alpha[b] = sum_h Q[d][h][a]*K[s][h][b]; softmax over b
// (scaled 1/4); msg[h] = sum_b att[b]*V[s][h][b]; atomicAdd attn[d][h*16+a].
// qkv bf16 layout: [n][Q(512) | K(512) | V(512)]. grid 2500 x 256.
__global__ __launch_bounds__(256) void edge_attn(
    const int* __restrict__ eidx, const __bf16* __restrict__ qkv,
    float* __restrict__ attn)
{
    int t = blockIdx.x * 256 + threadIdx.x;
    int e = t >> 4;
    int a = t & 15;
    int s = eidx[e];
    int d = eidx[N_EDGES + e];

    const __bf16* qr = qkv + (size_t)d * 1536;
    const __bf16* kr = qkv + (size_t)s * 1536 + 512;
    const __bf16* vr = qkv + (size_t)s * 1536 + 1024;

    float al[16];
    #pragma unroll
    for (int j = 0; j < 16; ++j) al[j] = 0.f;

    for (int h = 0; h < 32; ++h) {
        float qv = (float)qr[h * 16 + a];
        bf16x8 k0 = *(const bf16x8*)(kr + h * 16);
        bf16x8 k1 = *(const bf16x8*)(kr + h * 16 + 8);
        #pragma unroll
        for (int j = 0; j < 8; ++j) {
            al[j]     += qv * (float)k0[j];
            al[8 + j] += qv * (float)k1[j];
        }
    }

    float mx = al[0];
    #pragma unroll
    for (int j = 1; j < 16; ++j) mx = fmaxf(mx, al[j]);
    float sum = 0.f;
    #pragma unroll
    for (int j = 0; j < 16; ++j) {
        float p = __expf((al[j] - mx) * 0.25f);
        al[j] = p;
        sum += p;
    }
    float inv = 1.f / sum;
    #pragma unroll
    for (int j = 0; j < 16; ++j) al[j] *= inv;

    float* ab = attn + (size_t)d * 512 + a;
    for (int h = 0; h < 32; ++h) {
        bf16x8 v0 = *(const bf16x8*)(vr + h * 16);
        bf16x8 v1 = *(const bf16x8*)(vr + h * 16 + 8);
        float m = 0.f;
        #pragma unroll
        for (int j = 0; j < 8; ++j) {
            m += al[j]     * (float)v0[j];
            m += al[8 + j] * (float)v1[j];
        }
        atomicAdd(ab + h * 16, m);
    }
}

// out = LN(x + t1 [+ t2] + bias) * g + b.  One wave per row (4 f32/lane).
// grid 2500 x 256 (4 rows/block).
__global__ __launch_bounds__(256) void ln_fused(
    const float* __restrict__ x, const float* __restrict__ t1,
    const float* __restrict__ t2, const float* __restrict__ bias,
    const float* __restrict__ g, const float* __restrict__ b,
    float* __restrict__ out)
{
    int wv = threadIdx.x >> 6;
    int lane = threadIdx.x & 63;
    int row = blockIdx.x * 4 + wv;
    int c = lane * 4;
    size_t off = (size_t)row * 256 + c;

    float4 v = *(const float4*)(x + off);
    float4 u = *(const float4*)(t1 + off);
    v.x += u.x; v.y += u.y; v.z += u.z; v.w += u.w;
    if (t2) {
        float4 w = *(const float4*)(t2 + off);
        v.x += w.x; v.y += w.y; v.z += w.z; v.w += w.w;
    }
    float4 bi = *(const float4*)(bias + c);
    v.x += bi.x; v.y += bi.y; v.z += bi.z; v.w += bi.w;

    float sum = v.x + v.y + v.z + v.w;
    float sq  = v.x*v.x + v.y*v.y + v.z*v.z + v.w*v.w;
    #pragma unroll
    for (int m = 1; m < 64; m <<= 1) {
        sum += __shfl_xor(sum, m);
        sq  += __shfl_xor(sq,  m);
    }
    float mean = sum * (1.f / 256.f);
    float var  = sq * (1.f / 256.f) - mean * mean;
    float invs = rsqrtf(var + 1e-5f);

    float4 gg = *(const float4*)(g + c);
    float4 bb = *(const float4*)(b + c);
    float4 o;
    o.x = (v.x - mean) * invs * gg.x + bb.x;
    o.y = (v.y - mean) * invs * gg.y + bb.y;
    o.z = (v.z - mean) * invs * gg.z + bb.z;
    o.w = (v.w - mean) * invs * gg.w + bb.w;
    *(float4*)(out + off) = o;
}

extern "C" void kernel_launch(void* const* d_in, const int* in_sizes, int n_in,
                              void* d_out, int out_size, void* d_ws, size_t ws_size,
                              hipStream_t stream)
{
    const int*   eidx = (const int*)  d_in[0];
    const float* x_in = (const float*)d_in[1];
    const float* We   = (const float*)d_in[2];
    const float* Wq   = (const float*)d_in[3];
    const float* Wk   = (const float*)d_in[4];
    const float* Wv   = (const float*)d_in[5];
    const float* Wo   = (const float*)d_in[6];
    const float* bo   = (const float*)d_in[7];
    const float* lng  = (const float*)d_in[8];
    const float* lnb  = (const float*)d_in[9];
    const float* mlpW = (const float*)d_in[10];
    const float* mlpb = (const float*)d_in[11];
    float* out = (float*)d_out;

    // workspace layout (~92.2 MB)
    char* p = (char*)d_ws;
    __bf16* qkv = (__bf16*)p; p += (size_t)N_NODES * 1536 * 2;
    float* attn = (float*)p;  p += (size_t)N_NODES * 512 * 4;
    float* xe   = (float*)p;  p += (size_t)N_NODES * 256 * 4;
    float* h2   = (float*)p;  p += (size_t)N_NODES * 256 * 4;
    float* xb0  = (float*)p;  p += (size_t)N_NODES * 256 * 4;
    float* xb1  = (float*)p;  p += (size_t)N_NODES * 256 * 4;
    if ((size_t)(p - (char*)d_ws) > ws_size) return;  // ws too small: fail loudly

    dim3 blk(256);
    dim3 g256(157, 4);   // Nc=256
    dim3 g512(157, 8);   // Nc=512

    const float* xcur = x_in;
    int step = 0;
    for (int l = 0; l < NLAYERS; ++l) {
        for (int s = 0; s < 2; ++s) {
            size_t ls = (size_t)(l * 2 + s);
            // xe = xcur @ We^T
            gemm_bt<false><<<g256, blk, 0, stream>>>(xcur, We + ls * 65536, xe, nullptr,
                                                     N_NODES, 256, 256, 0);
            // Q|K|V (bf16) = xe @ {Wq,Wk,Wv}^T
            gemm_bt<true><<<g512, blk, 0, stream>>>(xe, Wq + ls * 131072, nullptr, qkv,
                                                    N_NODES, 256, 1536, 0);
            gemm_bt<true><<<g512, blk, 0, stream>>>(xe, Wk + ls * 131072, nullptr, qkv,
                                                    N_NODES, 256, 1536, 512);
            gemm_bt<true><<<g512, blk, 0, stream>>>(xe, Wv + ls * 131072, nullptr, qkv,
                                                    N_NODES, 256, 1536, 1024);
            hipMemsetAsync(attn, 0, (size_t)N_NODES * 512 * 4, stream);
            edge_attn<<<dim3(2500), blk, 0, stream>>>(eidx, qkv, attn);
            // h2 = attn @ Wo^T
            gemm_bt<false><<<g256, blk, 0, stream>>>(attn, Wo + ls * 131072, h2, nullptr,
                                                     N_NODES, 512, 256, 0);
            float* xnext = (step == 14) ? out : ((step & 1) ? xb1 : xb0);
            ln_fused<<<dim3(2500), blk, 0, stream>>>(xcur, xe, h2, bo + ls * 256,
                                                     lng + (size_t)(l * 3 + s) * 256,
                                                     lnb + (size_t)(l * 3 + s) * 256, xnext);
            xcur = xnext; ++step;
        }
        // MLP: t = x @ mlpW^T ; x = LN(x + t + mlp_b)
        gemm_bt<false><<<g256, blk, 0, stream>>>(xcur, mlpW + (size_t)l * 65536, h2, nullptr,
                                                 N_NODES, 256, 256, 0);
        float* xnext = (step == 14) ? out : ((step & 1) ? xb1 : xb0);
        ln_fused<<<dim3(2500), blk, 0, stream>>>(xcur, h2, nullptr, mlpb + (size_t)l * 256,
                                                 lng + (size_t)(l * 3 + 2) * 256,
                                                 lnb + (size_t)(l * 3 + 2) * 256, xnext);
        xcur = xnext; ++step;
    }
}

// Round 2
// 1506.528 us; speedup vs baseline: 3.1311x; 3.1311x over previous
//
#include <hip/hip_runtime.h>
#include <hip/hip_bf16.h>

#define N_NODES 10000
#define N_EDGES 40000
#define NLAYERS 5

typedef __bf16 bf16x8 __attribute__((ext_vector_type(8)));
typedef __bf16 bf16x4 __attribute__((ext_vector_type(4)));
typedef float  f32x4  __attribute__((ext_vector_type(4)));

__device__ __forceinline__ bf16x8 cvt8(float4 a, float4 b) {
    bf16x8 r;
    r[0] = (__bf16)a.x; r[1] = (__bf16)a.y; r[2] = (__bf16)a.z; r[3] = (__bf16)a.w;
    r[4] = (__bf16)b.x; r[5] = (__bf16)b.y; r[6] = (__bf16)b.z; r[7] = (__bf16)b.w;
    return r;
}

__device__ __forceinline__ void gload_lds16(const void* g, void* l) {
    __builtin_amdgcn_global_load_lds(
        (const __attribute__((address_space(1))) void*)g,
        (__attribute__((address_space(3))) void*)l, 16, 0, 0);
}

// ---------------- f32 -> bf16 conversion (8 elems/thread) ----------------
// dst index = ch*dstStride + r where e = ch*chunk + r; grid-stride over total8.
__global__ __launch_bounds__(256) void cvt_chunks(
    const float* __restrict__ s, __bf16* __restrict__ d,
    long chunk, long dstStride, long total8)
{
    for (long i = (long)blockIdx.x * blockDim.x + threadIdx.x; i < total8;
         i += (long)gridDim.x * blockDim.x) {
        long e = i * 8;
        long ch = e / chunk;
        long r  = e - ch * chunk;
        float4 a = *(const float4*)(s + e);
        float4 b = *(const float4*)(s + e + 4);
        *(bf16x8*)(d + ch * dstStride + r) = cvt8(a, b);
    }
}

// ---------------- LDS-staged bf16 GEMM: C = A[MxK] @ W[NcxK]^T ----------------
// tile 128x64, BK=64, 256 threads (4 waves, 2x2), XOR-swizzled LDS (both sides).
// MODE 0: f32 out, MODE 1: bf16 out.
template<int MODE>
__global__ __launch_bounds__(256) void gemm_lds(
    const __bf16* __restrict__ A, const __bf16* __restrict__ W,
    float* __restrict__ Cf, __bf16* __restrict__ Ch,
    int M, int K, int ldc, int coloff)
{
    __shared__ __bf16 As[128 * 64];   // 16 KB, rows of 128 B
    __shared__ __bf16 Wsh[64 * 64];   // 8 KB
    const int tid = threadIdx.x;
    const int ln  = tid & 63;
    const int wv  = tid >> 6;
    const int wr  = wv >> 1, wc = wv & 1;
    const int brow0 = blockIdx.x * 128;
    const int colb0 = blockIdx.y * 64;

    // staging geometry: chunk = 1 KB = 8 rows x 128 B; lane ln covers
    // row (ln>>3), 16 bytes at swizzled source col ((ln&7)^(ln>>3))*8 elems.
    const int srow = ln >> 3;
    const int scol = ((ln & 7) ^ srow) * 8;

    const int fr = ln & 15;            // fragment row
    const int kq = ln >> 4;            // k-quarter
    char* asb = (char*)As;
    char* wsb = (char*)Wsh;

    f32x4 acc[4][2];
    #pragma unroll
    for (int m = 0; m < 4; ++m)
        #pragma unroll
        for (int n = 0; n < 2; ++n) acc[m][n] = (f32x4){0.f, 0.f, 0.f, 0.f};

    const int nt = K >> 6;
    for (int t = 0; t < nt; ++t) {
        const int kk0 = t << 6;
        if (t) __syncthreads();
        // stage A: 16 chunks, 4 per wave
        #pragma unroll
        for (int c = 0; c < 4; ++c) {
            int ch = wv * 4 + c;
            int grow = brow0 + ch * 8 + srow;
            if (grow >= M) grow = M - 1;
            gload_lds16(A + (size_t)grow * K + kk0 + scol, asb + ch * 1024);
        }
        // stage W: 8 chunks, 2 per wave
        #pragma unroll
        for (int c = 0; c < 2; ++c) {
            int ch = wv * 2 + c;
            int grow = colb0 + ch * 8 + srow;
            gload_lds16(W + (size_t)grow * K + kk0 + scol, wsb + ch * 1024);
        }
        __syncthreads();   // compiler emits vmcnt(0) drain here
        #pragma unroll
        for (int ks = 0; ks < 2; ++ks) {
            const int kb = ks * 64 + kq * 16;        // byte col within row
            const int sw = (fr & 7) << 4;
            bf16x8 af[4], wf[2];
            #pragma unroll
            for (int m = 0; m < 4; ++m) {
                int row = wr * 64 + m * 16 + fr;
                af[m] = *(const bf16x8*)(asb + row * 128 + (kb ^ sw));
            }
            #pragma unroll
            for (int n = 0; n < 2; ++n) {
                int row = wc * 32 + n * 16 + fr;
                wf[n] = *(const bf16x8*)(wsb + row * 128 + (kb ^ sw));
            }
            #pragma unroll
            for (int m = 0; m < 4; ++m)
                #pragma unroll
                for (int n = 0; n < 2; ++n)
                    acc[m][n] = __builtin_amdgcn_mfma_f32_16x16x32_bf16(
                        af[m], wf[n], acc[m][n], 0, 0, 0);
        }
    }

    const int rq = (ln >> 4) * 4;
    #pragma unroll
    for (int m = 0; m < 4; ++m) {
        #pragma unroll
        for (int rr = 0; rr < 4; ++rr) {
            int orow = brow0 + wr * 64 + m * 16 + rq + rr;
            if (orow < M) {
                size_t o = (size_t)orow * ldc + coloff + colb0 + wc * 32 + fr;
                #pragma unroll
                for (int n = 0; n < 2; ++n) {
                    if (MODE == 0) Cf[o + n * 16] = acc[m][n][rr];
                    else           Ch[o + n * 16] = (__bf16)acc[m][n][rr];
                }
            }
        }
    }
}

// ---------------- per-edge 16x16 attention + scatter-add ----------------
// qkv bf16 layout: [n][Q(512) | K(512) | V(512)].
__global__ __launch_bounds__(256) void edge_attn(
    const int* __restrict__ eidx, const __bf16* __restrict__ qkv,
    float* __restrict__ attn)
{
    int t = blockIdx.x * 256 + threadIdx.x;
    int e = t >> 4;
    int a = t & 15;
    int s = eidx[e];
    int d = eidx[N_EDGES + e];

    const __bf16* qr = qkv + (size_t)d * 1536;
    const __bf16* kr = qkv + (size_t)s * 1536 + 512;
    const __bf16* vr = qkv + (size_t)s * 1536 + 1024;

    float al[16];
    #pragma unroll
    for (int j = 0; j < 16; ++j) al[j] = 0.f;

    for (int h = 0; h < 32; ++h) {
        float qv = (float)qr[h * 16 + a];
        bf16x8 k0 = *(const bf16x8*)(kr + h * 16);
        bf16x8 k1 = *(const bf16x8*)(kr + h * 16 + 8);
        #pragma unroll
        for (int j = 0; j < 8; ++j) {
            al[j]     += qv * (float)k0[j];
            al[8 + j] += qv * (float)k1[j];
        }
    }

    float mx = al[0];
    #pragma unroll
    for (int j = 1; j < 16; ++j) mx = fmaxf(mx, al[j]);
    float sum = 0.f;
    #pragma unroll
    for (int j = 0; j < 16; ++j) {
        float p = __expf((al[j] - mx) * 0.25f);
        al[j] = p;
        sum += p;
    }
    float inv = 1.f / sum;
    #pragma unroll
    for (int j = 0; j < 16; ++j) al[j] *= inv;

    float* ab = attn + (size_t)d * 512 + a;
    for (int h = 0; h < 32; ++h) {
        bf16x8 v0 = *(const bf16x8*)(vr + h * 16);
        bf16x8 v1 = *(const bf16x8*)(vr + h * 16 + 8);
        float m = 0.f;
        #pragma unroll
        for (int j = 0; j < 8; ++j) {
            m += al[j]     * (float)v0[j];
            m += al[8 + j] * (float)v1[j];
        }
        atomicAdd(ab + h * 16, m);
    }
}

// ---------------- fused residual + LayerNorm ----------------
// out = LN(x + (tb?) + tf + bias); writes f32 (and optional bf16 copy).
__global__ __launch_bounds__(256) void ln_fused(
    const float* __restrict__ x, const __bf16* __restrict__ tb,
    const float* __restrict__ tf, const float* __restrict__ bias,
    const float* __restrict__ g, const float* __restrict__ b,
    float* __restrict__ outf, __bf16* __restrict__ outb)
{
    int wv = threadIdx.x >> 6;
    int lane = threadIdx.x & 63;
    int row = blockIdx.x * 4 + wv;
    int c = lane * 4;
    size_t off = (size_t)row * 256 + c;

    float4 v = *(const float4*)(x + off);
    float4 u = *(const float4*)(tf + off);
    v.x += u.x; v.y += u.y; v.z += u.z; v.w += u.w;
    if (tb) {
        bf16x4 w = *(const bf16x4*)(tb + off);
        v.x += (float)w[0]; v.y += (float)w[1]; v.z += (float)w[2]; v.w += (float)w[3];
    }
    float4 bi = *(const float4*)(bias + c);
    v.x += bi.x; v.y += bi.y; v.z += bi.z; v.w += bi.w;

    float sum = v.x + v.y + v.z + v.w;
    float sq  = v.x*v.x + v.y*v.y + v.z*v.z + v.w*v.w;
    #pragma unroll
    for (int m = 1; m < 64; m <<= 1) {
        sum += __shfl_xor(sum, m);
        sq  += __shfl_xor(sq,  m);
    }
    float mean = sum * (1.f / 256.f);
    float var  = sq * (1.f / 256.f) - mean * mean;
    float invs = rsqrtf(var + 1e-5f);

    float4 gg = *(const float4*)(g + c);
    float4 bb = *(const float4*)(b + c);
    float4 o;
    o.x = (v.x - mean) * invs * gg.x + bb.x;
    o.y = (v.y - mean) * invs * gg.y + bb.y;
    o.z = (v.z - mean) * invs * gg.z + bb.z;
    o.w = (v.w - mean) * invs * gg.w + bb.w;
    *(float4*)(outf + off) = o;
    if (outb) {
        bf16x4 ob;
        ob[0] = (__bf16)o.x; ob[1] = (__bf16)o.y;
        ob[2] = (__bf16)o.z; ob[3] = (__bf16)o.w;
        *(bf16x4*)(outb + off) = ob;
    }
}

extern "C" void kernel_launch(void* const* d_in, const int* in_sizes, int n_in,
                              void* d_out, int out_size, void* d_ws, size_t ws_size,
                              hipStream_t stream)
{
    const int*   eidx = (const int*)  d_in[0];
    const float* x_in = (const float*)d_in[1];
    const float* We   = (const float*)d_in[2];
    const float* Wq   = (const float*)d_in[3];
    const float* Wk   = (const float*)d_in[4];
    const float* Wv   = (const float*)d_in[5];
    const float* Wo   = (const float*)d_in[6];
    const float* bo   = (const float*)d_in[7];
    const float* lng  = (const float*)d_in[8];
    const float* lnb  = (const float*)d_in[9];
    const float* mlpW = (const float*)d_in[10];
    const float* mlpb = (const float*)d_in[11];
    float* out = (float*)d_out;

    // workspace layout (~84.1 MB)
    char* p = (char*)d_ws;
    __bf16* wE   = (__bf16*)p; p += (size_t)10 * 65536  * 2;   // [10][256][256]
    __bf16* wQKV = (__bf16*)p; p += (size_t)10 * 393216 * 2;   // [10][1536][256]
    __bf16* wO   = (__bf16*)p; p += (size_t)10 * 131072 * 2;   // [10][256][512]
    __bf16* wM   = (__bf16*)p; p += (size_t)5  * 65536  * 2;   // [5][256][256]
    __bf16* qkv  = (__bf16*)p; p += (size_t)N_NODES * 1536 * 2;
    float*  attn = (float*) p; p += (size_t)N_NODES * 512 * 4;
    __bf16* xeb  = (__bf16*)p; p += (size_t)N_NODES * 256 * 2;
    float*  xbf  = (float*) p; p += (size_t)N_NODES * 256 * 4;
    __bf16* xbb  = (__bf16*)p; p += (size_t)N_NODES * 256 * 2;
    if ((size_t)(p - (char*)d_ws) > ws_size) return;
    float*  h2      = attn;           // alias: attn f32 dead after cvt
    __bf16* attn_bf = qkv;            // alias: qkv dead after edge_attn

    dim3 blk(256);
    auto cvtg = [](long total8) { long g = (total8 + 255) / 256; return dim3((unsigned)(g > 2048 ? 2048 : g)); };

    // ---- once per call: weights + x_in to bf16 ----
    cvt_chunks<<<cvtg(81920), blk, 0, stream>>>(We,   wE,            65536,  65536, 81920);
    cvt_chunks<<<cvtg(163840), blk, 0, stream>>>(Wq,  wQKV,          131072, 393216, 163840);
    cvt_chunks<<<cvtg(163840), blk, 0, stream>>>(Wk,  wQKV + 131072, 131072, 393216, 163840);
    cvt_chunks<<<cvtg(163840), blk, 0, stream>>>(Wv,  wQKV + 262144, 131072, 393216, 163840);
    cvt_chunks<<<cvtg(163840), blk, 0, stream>>>(Wo,  wO,            131072, 131072, 163840);
    cvt_chunks<<<cvtg(40960), blk, 0, stream>>>(mlpW, wM,            65536,  65536, 40960);
    cvt_chunks<<<cvtg(320000), blk, 0, stream>>>(x_in, xbb,          2560000, 2560000, 320000);

    dim3 gN256(79, 4);    // Nc=256
    dim3 gQKV(79, 24);    // Nc=1536

    const float* xcur_f = x_in;
    int step = 0;
    for (int l = 0; l < NLAYERS; ++l) {
        for (int s = 0; s < 2; ++s) {
            size_t ls = (size_t)(l * 2 + s);
            // xe (bf16) = x @ We^T
            gemm_lds<1><<<gN256, blk, 0, stream>>>(xbb, wE + ls * 65536, nullptr, xeb,
                                                   N_NODES, 256, 256, 0);
            // qkv (bf16) = xe @ [Wq;Wk;Wv]^T
            gemm_lds<1><<<gQKV, blk, 0, stream>>>(xeb, wQKV + ls * 393216, nullptr, qkv,
                                                  N_NODES, 256, 1536, 0);
            hipMemsetAsync(attn, 0, (size_t)N_NODES * 512 * 4, stream);
            edge_attn<<<dim3(2500), blk, 0, stream>>>(eidx, qkv, attn);
            // attn -> bf16 (into dead qkv buffer)
            cvt_chunks<<<cvtg(640000), blk, 0, stream>>>(attn, attn_bf, 5120000, 5120000, 640000);
            // h2 (f32, aliases attn) = attn_bf @ Wo^T
            gemm_lds<0><<<gN256, blk, 0, stream>>>(attn_bf, wO + ls * 131072, h2, nullptr,
                                                   N_NODES, 512, 256, 0);
            bool last = (step == 14);
            ln_fused<<<dim3(2500), blk, 0, stream>>>(xcur_f, xeb, h2, bo + ls * 256,
                                                     lng + (size_t)(l * 3 + s) * 256,
                                                     lnb + (size_t)(l * 3 + s) * 256,
                                                     last ? out : xbf, last ? nullptr : xbb);
            xcur_f = xbf; ++step;
        }
        // MLP
        gemm_lds<0><<<gN256, blk, 0, stream>>>(xbb, wM + (size_t)l * 65536, h2, nullptr,
                                               N_NODES, 256, 256, 0);
        bool last = (step == 14);
        ln_fused<<<dim3(2500), blk, 0, stream>>>(xcur_f, nullptr, h2, mlpb + (size_t)l * 256,
                                                 lng + (size_t)(l * 3 + 2) * 256,
                                                 lnb + (size_t)(l * 3 + 2) * 256,
                                                 last ? out : xbf, last ? nullptr : xbb);
        xcur_f = xbf; ++step;
    }
}